// Round 10
// baseline (196.239 us; speedup 1.0000x reference)
//
#include <hip/hip_runtime.h>
#include <cstdint>

typedef unsigned short u16;
typedef __bf16 bf16x8 __attribute__((ext_vector_type(8)));
typedef __bf16 bf16x2 __attribute__((ext_vector_type(2)));
typedef float floatx4 __attribute__((ext_vector_type(4)));
typedef unsigned short u16x4 __attribute__((ext_vector_type(4)));
typedef unsigned short u16x8 __attribute__((ext_vector_type(8)));

#define MFMA16(a, b, c) __builtin_amdgcn_mfma_f32_16x16x32_bf16((a), (b), (c), 0, 0, 0)
// 0.125 * log2(e): folded into Q so softmax is exp2(st) with no per-elem mul.
#define QSCALE_LOG2E 0.18033688011112042f

// ---- helpers -------------------------------------------------------------

typedef __attribute__((address_space(3))) void as3_void;
typedef __attribute__((address_space(1))) void as1_void;

static __device__ __forceinline__ void async_load16(const void* g, void* l) {
  __builtin_amdgcn_global_load_lds((as1_void*)(uintptr_t)g, (as3_void*)(uintptr_t)l,
                                   16, 0, 0);
}

static __device__ __forceinline__ u16 f2bf(float f) {
  union { float f; unsigned int u; } v; v.f = f;
  unsigned int u = v.u;
  u += 0x7fffu + ((u >> 16) & 1u);   // RNE
  return (u16)(u >> 16);
}

static __device__ __forceinline__ u16x4 pack_bf4(float a, float b, float c, float d) {
#if __has_builtin(__builtin_amdgcn_cvt_pk_bf16_f32)
  union { u16x4 v4; bf16x2 v2[2]; } u;
  u.v2[0] = __builtin_amdgcn_cvt_pk_bf16_f32(a, b);
  u.v2[1] = __builtin_amdgcn_cvt_pk_bf16_f32(c, d);
  return u.v4;
#else
  u16x4 r; r[0] = f2bf(a); r[1] = f2bf(b); r[2] = f2bf(c); r[3] = f2bf(d);
  return r;
#endif
}

static __device__ __forceinline__ float fast_exp2(float x) {
#if __has_builtin(__builtin_amdgcn_exp2f)
  return __builtin_amdgcn_exp2f(x);
#else
  return exp2f(x);
#endif
}

// ---- fused: 4x weight transpose+convert (z=0..3) + x convert (z=4) -------

__global__ __launch_bounds__(256) void prep_kernel(
    const float* __restrict__ w0, const float* __restrict__ w1,
    const float* __restrict__ w2, const float* __restrict__ w3,
    u16* __restrict__ wout,
    const float* __restrict__ xin, u16* __restrict__ xout) {
  if (blockIdx.z == 4) {
    int blk = blockIdx.y * 16 + blockIdx.x;
    size_t base = (size_t)blk * 16384 + (size_t)threadIdx.x * 8;
#pragma unroll
    for (int r = 0; r < 8; r++) {
      size_t i = base + (size_t)r * 2048;
      float4 a = *(const float4*)(xin + i);
      float4 b = *(const float4*)(xin + i + 4);
      u16x8 o;
      o[0] = f2bf(a.x); o[1] = f2bf(a.y); o[2] = f2bf(a.z); o[3] = f2bf(a.w);
      o[4] = f2bf(b.x); o[5] = f2bf(b.y); o[6] = f2bf(b.z); o[7] = f2bf(b.w);
      *(u16x8*)(xout + i) = o;
    }
    return;
  }
  __shared__ u16 t[64][65];
  const float* in = (blockIdx.z == 0) ? w0 : (blockIdx.z == 1) ? w1
                    : (blockIdx.z == 2) ? w2 : w3;
  u16* oz = wout + (size_t)blockIdx.z * (1024 * 1024);
  const int tid = threadIdx.x;
  const int x = tid & 63, y0 = tid >> 6;
  const int bx = blockIdx.x * 64, by = blockIdx.y * 64;
#pragma unroll
  for (int p = 0; p < 16; p++) {
    int y = y0 + p * 4;
    t[y][x] = f2bf(in[(size_t)(by + y) * 1024 + bx + x]);
  }
  __syncthreads();
#pragma unroll
  for (int p = 0; p < 16; p++) {
    int r = y0 + p * 4;
    oz[(size_t)(bx + r) * 1024 + by + x] = t[x][r];
  }
}

// ---- QKV GEMM: C[4096][1024] = X @ Wz, Wz given transposed [N][K] --------
// 128x128 tile, BK=32, 4 waves, global_load_lds staging, XOR-swizzled octets.
// z==0 (Q): pre-scaled by QSCALE_LOG2E, row-major out.
// z==1 (K): row-major out.
// z==2 (V): written as V^T[bh][64][2048] via an LDS-transposed coalesced
//           epilogue (256B-contiguous segments).

__global__ __launch_bounds__(256, 3) void gemm_qkv_kernel(
    const u16* __restrict__ A, const u16* __restrict__ BT,
    u16* __restrict__ out, u16* __restrict__ outVT) {
  __shared__ u16 As[128 * 32];
  __shared__ u16 Bs[128 * 32];
  __shared__ u16 tb[64 * 136];       // V^T staging (z==2 epilogue only)
  const int tid = threadIdx.x;
  const int w = tid >> 6, lane = tid & 63;
  const int bm = blockIdx.y * 128, bn = blockIdx.x * 128;
  const int z = blockIdx.z;
  const int K = 1024, N = 1024;
  const u16* Bz = BT + (size_t)z * N * K;

  const int c0 = w * 2, c1 = c0 + 1;
  const int mA0 = c0 * 16 + (lane >> 2), mA1 = c1 * 16 + (lane >> 2);
  const int kg0 = (lane & 3) ^ ((mA0 >> 1) & 3);
  const int kg1 = (lane & 3) ^ ((mA1 >> 1) & 3);
  const u16* agp0 = A + (size_t)(bm + mA0) * K + kg0 * 8;
  const u16* agp1 = A + (size_t)(bm + mA1) * K + kg1 * 8;
  const u16* bgp0 = Bz + (size_t)(bn + mA0) * K + kg0 * 8;
  const u16* bgp1 = Bz + (size_t)(bn + mA1) * K + kg1 * 8;
  u16* ald0 = As + c0 * 512; u16* ald1 = As + c1 * 512;
  u16* bld0 = Bs + c0 * 512; u16* bld1 = Bs + c1 * 512;

  const int wm = (w >> 1) * 64, wn = (w & 1) * 64;
  floatx4 acc[4][4] = {};

  int a_off[4], b_off[4];
#pragma unroll
  for (int i = 0; i < 4; i++) {
    int m = wm + i * 16 + (lane & 15);
    a_off[i] = m * 32 + (((lane >> 4) ^ ((m >> 1) & 3)) * 8);
    int n = wn + i * 16 + (lane & 15);
    b_off[i] = n * 32 + (((lane >> 4) ^ ((n >> 1) & 3)) * 8);
  }

  for (int k0 = 0; k0 < K; k0 += 32) {
    __syncthreads();
    async_load16(agp0 + k0, ald0);
    async_load16(agp1 + k0, ald1);
    async_load16(bgp0 + k0, bld0);
    async_load16(bgp1 + k0, bld1);
    __syncthreads();
    bf16x8 af[4], bf[4];
#pragma unroll
    for (int i = 0; i < 4; i++) af[i] = *(const bf16x8*)(As + a_off[i]);
#pragma unroll
    for (int j = 0; j < 4; j++) bf[j] = *(const bf16x8*)(Bs + b_off[j]);
#pragma unroll
    for (int i = 0; i < 4; i++)
#pragma unroll
      for (int j = 0; j < 4; j++)
        acc[i][j] = MFMA16(af[i], bf[j], acc[i][j]);
  }

  // epilogue: C/D layout col=lane&15, row=(lane>>4)*4+reg  [m89]
  const int roff = (lane >> 4) * 4;
  const int coff = lane & 15;
  if (z == 2) {
    // V^T: two 64-col halves through padded LDS, then coalesced b128 stores
    const int b = bm >> 11, s0 = bm & 2047;
#pragma unroll
    for (int half = 0; half < 2; half++) {
      __syncthreads();
      if ((w & 1) == half) {
#pragma unroll
        for (int i = 0; i < 4; i++) {
          int s_local = wm + i * 16 + roff;
#pragma unroll
          for (int j = 0; j < 4; j++) {
            int c_local = j * 16 + coff;     // 0..63 within half
            u16x4 pk = pack_bf4(acc[i][j][0], acc[i][j][1],
                                acc[i][j][2], acc[i][j][3]);
            *(u16x4*)(tb + c_local * 136 + s_local) = pk;
          }
        }
      }
      __syncthreads();
      // store: 16 consecutive lanes cover one d-row's 128 s (256B contiguous)
#pragma unroll
      for (int p = 0; p < 4; p++) {
        int c_local = (tid >> 4) & 15;       // 0..15
        int row = p * 16 + c_local;          // 0..63
        int so = tid & 15;
        int cg = bn + half * 64 + row;
        int h = cg >> 6, d = cg & 63;
        u16x8 vv = *(const u16x8*)(tb + row * 136 + so * 8);
        *(u16x8*)(outVT + ((size_t)(b * 16 + h) * 64 + d) * 2048 + s0 + so * 8) = vv;
      }
    }
  } else {
    const float sc = (z == 0) ? QSCALE_LOG2E : 1.0f;
    u16* outz = out + (size_t)z * 4096 * 1024;
#pragma unroll
    for (int i = 0; i < 4; i++) {
      int r0 = bm + wm + i * 16 + roff;
#pragma unroll
      for (int j = 0; j < 4; j++) {
        int c = bn + wn + j * 16 + coff;
#pragma unroll
        for (int r = 0; r < 4; r++)
          outz[(size_t)(r0 + r) * N + c] = f2bf(acc[i][j][r] * sc);
      }
    }
  }
}

// ---- O GEMM: out[4096][1024] f32 = CTX @ Wo + bo -------------------------
// 128m x 64n tile, BK=32, 4 waves (2x2 of 64x32) -> 512 blocks = 2/CU.

__global__ __launch_bounds__(256, 2) void gemm_o_kernel(
    const u16* __restrict__ A, const u16* __restrict__ BT,
    const float* __restrict__ bias, float* __restrict__ out) {
  __shared__ u16 As[128 * 32];
  __shared__ u16 Bs[64 * 32];
  const int tid = threadIdx.x;
  const int w = tid >> 6, lane = tid & 63;
  const int bm = blockIdx.y * 128, bn = blockIdx.x * 64;
  const int K = 1024, N = 1024;

  const u16* gp[3]; u16* ld[3];
#pragma unroll
  for (int i = 0; i < 3; i++) {
    int c = w * 3 + i;
    if (c < 8) {
      int m = c * 16 + (lane >> 2);
      int kg = (lane & 3) ^ ((m >> 1) & 3);
      gp[i] = A + (size_t)(bm + m) * K + kg * 8;
      ld[i] = As + c * 512;
    } else {
      int cb = c - 8;
      int n = cb * 16 + (lane >> 2);
      int kg = (lane & 3) ^ ((n >> 1) & 3);
      gp[i] = BT + (size_t)(bn + n) * K + kg * 8;
      ld[i] = Bs + cb * 512;
    }
  }

  const int wm = (w >> 1) * 64, wn = (w & 1) * 32;
  floatx4 acc[4][2] = {};

  int a_off[4], b_off[2];
#pragma unroll
  for (int i = 0; i < 4; i++) {
    int m = wm + i * 16 + (lane & 15);
    a_off[i] = m * 32 + (((lane >> 4) ^ ((m >> 1) & 3)) * 8);
  }
#pragma unroll
  for (int j = 0; j < 2; j++) {
    int n = wn + j * 16 + (lane & 15);
    b_off[j] = n * 32 + (((lane >> 4) ^ ((n >> 1) & 3)) * 8);
  }

  for (int k0 = 0; k0 < K; k0 += 32) {
    __syncthreads();
    async_load16(gp[0] + k0, ld[0]);
    async_load16(gp[1] + k0, ld[1]);
    async_load16(gp[2] + k0, ld[2]);
    __syncthreads();
    bf16x8 af[4], bf[2];
#pragma unroll
    for (int i = 0; i < 4; i++) af[i] = *(const bf16x8*)(As + a_off[i]);
#pragma unroll
    for (int j = 0; j < 2; j++) bf[j] = *(const bf16x8*)(Bs + b_off[j]);
#pragma unroll
    for (int i = 0; i < 4; i++)
#pragma unroll
      for (int j = 0; j < 2; j++)
        acc[i][j] = MFMA16(af[i], bf[j], acc[i][j]);
  }

  const int roff = (lane >> 4) * 4;
  const int coff = lane & 15;
#pragma unroll
  for (int i = 0; i < 4; i++) {
    int r0 = bm + wm + i * 16 + roff;
#pragma unroll
    for (int j = 0; j < 2; j++) {
      int c = bn + wn + j * 16 + coff;
      float bv = bias[c];
#pragma unroll
      for (int r = 0; r < 4; r++)
        out[(size_t)(r0 + r) * N + c] = acc[i][j][r] + bv;
    }
  }
}

// ---- flash attention (no-max softmax, s-SPLIT wave pairs) ----------------
// Q (pre-scaled), K: [b*2048+s][1024] row-major bf16, head at col h*64.
// VT: [bh][64][2048] bf16.  ctx: [b][s][1024] bf16.
// Block = 4 waves over a 128q x 128s tile: wave (qh,sh) handles q-half qh
// (64 rows, in registers as B-operand) x s-half sh (64 cols).  Each wave
// reads only HALF of K and V from LDS: 24 b128/wave-iter vs 40 in the
// q-split layout (the LDS data pipe was the measured ~64%-busy ceiling).
// No-max softmax makes the s-split free: partial O and partial l=sum(P)
// are additive; one LDS combine in the epilogue (sh==1 dumps into the dead
// Ks/Vs space, sh==0 adds and stores).  Row-sum via MFMA vs all-ones.
// Ps stride 68 u16 (bank stride 34===2 mod 32 -> the 16 q-lanes of a quad
// hit 16 distinct even banks: conflict-free P access).
// XCD swizzle: bid&7 pins 4 heads' K/V into one XCD's L2 (FETCH 12 MB).

__global__ __launch_bounds__(256, 2) void attn_kernel(
    const u16* __restrict__ Q, const u16* __restrict__ Kx,
    const u16* __restrict__ VT, u16* __restrict__ ctx) {
  // one LDS arena: Ks [128s][64d] | Vs [64d][128s] | Ps 4 x [64q][68]
  __shared__ __align__(16) u16 lds[8192 + 8192 + 4 * 64 * 68];   // 66 KB
  u16* Ks = lds;
  u16* Vs = lds + 8192;
  u16* Ps = lds + 16384;
  const int tid = threadIdx.x;
  const int w = tid >> 6, lane = tid & 63;
  const int qh = w >> 1, sh = w & 1;
  const int bid = blockIdx.x;
  const int bh = (bid >> 7) * 8 + (bid & 7);      // XCD-pinned head group
  const int q0 = ((bid >> 3) & 15) * 128;
  const int b = bh >> 4, h = bh & 15;
  const u16* Qh = Q + (size_t)b * 2048 * 1024 + h * 64;
  const u16* Kh = Kx + (size_t)b * 2048 * 1024 + h * 64;
  const u16* Vh = VT + (size_t)bh * 64 * 2048;
  const int quad = lane >> 4;

  // Q fragments: 64 q-rows/wave (B-operand: col=lane&15, k-octet=quad)
  const int qbase = q0 + qh * 64;
  bf16x8 qf[4][2];
#pragma unroll
  for (int qt = 0; qt < 4; qt++)
#pragma unroll
    for (int ks = 0; ks < 2; ks++)
      qf[qt][ks] = *(const bf16x8*)(Qh + (size_t)(qbase + qt * 16 + (lane & 15)) * 1024 +
                                    ks * 32 + quad * 8);

  bf16x8 onesf;
#pragma unroll
  for (int i = 0; i < 8; i++) onesf[i] = (__bf16)1.0f;
  const floatx4 zero4 = {};

  // staging: wave w owns Ks/Vs chunks w*4..w*4+3 (1KB each), async DMA
  const u16* kgp[4]; const u16* vgp[4];
  u16* kld[4]; u16* vld[4];
#pragma unroll
  for (int i = 0; i < 4; i++) {
    int c = w * 4 + i;
    int sl = c * 8 + (lane >> 3);
    int dg = (lane & 7) ^ (lane >> 3);
    kgp[i] = Kh + (size_t)sl * 1024 + dg * 8;
    kld[i] = Ks + c * 512;
    int dl = c * 4 + quad;
    int sg = (lane & 15) ^ (dl & 15);
    vgp[i] = Vh + (size_t)dl * 2048 + sg * 8;
    vld[i] = Vs + c * 512;
  }

  // K-fragment LDS bases for this wave's s-half (slabs sh*4 .. sh*4+3)
  const int slot_k0 = quad ^ (lane & 7);
  const int slot_k1 = (4 + quad) ^ (lane & 7);
  const u16* kf0_base = Ks + sh * 4096 + (lane & 15) * 64 + slot_k0 * 8;
  const u16* kf1_base = Ks + sh * 4096 + (lane & 15) * 64 + slot_k1 * 8;

  floatx4 o[4][4] = {};
  floatx4 lacc[4] = {};              // partial row sums (this s-half)
  u16* Pw = Ps + w * (64 * 68);
  int qrow[4];
#pragma unroll
  for (int qt = 0; qt < 4; qt++) qrow[qt] = (qt * 16 + (lane & 15)) * 68;

  for (int t = 0; t < 16; t++) {
    const size_t k0 = (size_t)t * 128;
    __syncthreads();
#pragma unroll
    for (int i = 0; i < 4; i++) {
      async_load16(kgp[i] + k0 * 1024, kld[i]);
      async_load16(vgp[i] + k0, vld[i]);
    }
    __syncthreads();

    // QK for this wave's 4 slabs (batched: 32 MFMAs in flight)
    floatx4 st[4][4];
#pragma unroll
    for (int si = 0; si < 4; si++) {
      bf16x8 kf0 = *(const bf16x8*)(kf0_base + si * 1024);
      bf16x8 kf1 = *(const bf16x8*)(kf1_base + si * 1024);
#pragma unroll
      for (int qt = 0; qt < 4; qt++)
        st[si][qt] = MFMA16(kf1, qf[qt][1], MFMA16(kf0, qf[qt][0], zero4));
    }
    // p = exp2(st); pack + write P [q][s_local] (s_local = si*16 + quad*4)
#pragma unroll
    for (int si = 0; si < 4; si++)
#pragma unroll
      for (int qt = 0; qt < 4; qt++) {
        u16x4 pk = pack_bf4(fast_exp2(st[si][qt][0]), fast_exp2(st[si][qt][1]),
                            fast_exp2(st[si][qt][2]), fast_exp2(st[si][qt][3]));
        *(u16x4*)(Pw + qrow[qt] + si * 16 + quad * 4) = pk;
      }

    // O += P . V over this s-half's two 32-s blocks
#pragma unroll
    for (int ksl = 0; ksl < 2; ksl++) {
      int kb = sh * 2 + ksl;
      bf16x8 vf[4];
#pragma unroll
      for (int jt = 0; jt < 4; jt++) {
        int d = jt * 16 + (lane & 15);
        int slot = (kb * 4 + quad) ^ (d & 15);
        vf[jt] = *(const bf16x8*)(Vs + d * 128 + slot * 8);
      }
#pragma unroll
      for (int qt = 0; qt < 4; qt++) {
        bf16x8 pf = *(const bf16x8*)(Pw + qrow[qt] + ksl * 32 + quad * 8);
#pragma unroll
        for (int jt = 0; jt < 4; jt++)
          o[qt][jt] = MFMA16(pf, vf[jt], o[qt][jt]);
        lacc[qt] = MFMA16(pf, onesf, lacc[qt]);
      }
    }
  }

  // combine s-halves: sh==1 dumps O,l into Ks/Vs space; sh==0 adds + stores
  __syncthreads();
  floatx4* dump  = (floatx4*)lds;            // 2048 x 16B = Ks+Vs (32 KB)
  floatx4* ldump = (floatx4*)(lds + 16384);  // in Ps region
  if (sh == 1) {
    int base = qh * 1024;
#pragma unroll
    for (int qt = 0; qt < 4; qt++)
#pragma unroll
      for (int jt = 0; jt < 4; jt++)
        dump[base + (qt * 4 + jt) * 64 + lane] = o[qt][jt];
#pragma unroll
    for (int i = 0; i < 4; i++)
      ldump[qh * 256 + i * 64 + lane] = lacc[i];
  }
  __syncthreads();
  if (sh == 0) {
    int base = qh * 1024;
#pragma unroll
    for (int qt = 0; qt < 4; qt++)
#pragma unroll
      for (int jt = 0; jt < 4; jt++)
        o[qt][jt] += dump[base + (qt * 4 + jt) * 64 + lane];
#pragma unroll
    for (int i = 0; i < 4; i++)
      lacc[i] += ldump[qh * 256 + i * 64 + lane];
    // epilogue: ctx[b][s][h*64+d] bf16; lacc rows coincide with o rows
#pragma unroll
    for (int qt = 0; qt < 4; qt++)
#pragma unroll
      for (int r = 0; r < 4; r++) {
        float inv = 1.0f / lacc[qt][r];
        int s = qbase + qt * 16 + quad * 4 + r;
#pragma unroll
        for (int j = 0; j < 4; j++) {
          int c = h * 64 + j * 16 + (lane & 15);
          ctx[(size_t)(b * 2048 + s) * 1024 + c] = f2bf(o[qt][j][r] * inv);
        }
      }
  }
}

// ---- launch --------------------------------------------------------------
// ws layout (u16 elements, MM = 1024*1024):
//   [0,3MM)    WqT,WkT,WvT bf16        [3MM,4MM)  WoT bf16
//   [4MM,8MM)  x converted to bf16     [8MM,20MM) Q,K row-major (V slot unused)
//   [20MM,24MM) V^T bf16               [24MM,28MM) ctx bf16

extern "C" void kernel_launch(void* const* d_in, const int* in_sizes, int n_in,
                              void* d_out, int out_size, void* d_ws, size_t ws_size,
                              hipStream_t stream) {
  (void)in_sizes; (void)n_in; (void)out_size; (void)ws_size;
  const float* x  = (const float*)d_in[0];
  const float* Wq = (const float*)d_in[1];
  const float* Wk = (const float*)d_in[2];
  const float* Wv = (const float*)d_in[3];
  const float* Wo = (const float*)d_in[4];
  const float* bo = (const float*)d_in[5];
  u16* ws = (u16*)d_ws;
  const size_t MM = 1024 * 1024;
  u16* WT  = ws;             // 3 x [1024][1024] (Wq,Wk,Wv transposed)
  u16* WoT = ws + 3 * MM;    // [1024][1024]
  u16* Xb  = ws + 4 * MM;    // [4096][1024]
  u16* QKV = ws + 8 * MM;    // Q,K row-major [4096][1024] each
  u16* VTp = ws + 20 * MM;   // [32][64][2048]
  u16* CTX = ws + 24 * MM;   // [4096][1024]

  dim3 blk(256);
  prep_kernel<<<dim3(16, 16, 5), blk, 0, stream>>>(Wq, Wk, Wv, Wo, WT, x, Xb);
  gemm_qkv_kernel<<<dim3(8, 32, 3), blk, 0, stream>>>(Xb, WT, QKV, VTp);
  attn_kernel<<<dim3(512, 1, 1), blk, 0, stream>>>(QKV, QKV + 4 * MM, VTp, CTX);
  gemm_o_kernel<<<dim3(16, 32, 1), blk, 0, stream>>>(CTX, WoT, bo, (float*)d_out);
}

// Round 11
// 184.476 us; speedup vs baseline: 1.0638x; 1.0638x over previous
//
#include <hip/hip_runtime.h>
#include <cstdint>

typedef unsigned short u16;
typedef __bf16 bf16x8 __attribute__((ext_vector_type(8)));
typedef __bf16 bf16x2 __attribute__((ext_vector_type(2)));
typedef float floatx4 __attribute__((ext_vector_type(4)));
typedef unsigned short u16x4 __attribute__((ext_vector_type(4)));
typedef unsigned short u16x8 __attribute__((ext_vector_type(8)));

#define MFMA16(a, b, c) __builtin_amdgcn_mfma_f32_16x16x32_bf16((a), (b), (c), 0, 0, 0)
// 0.125 * log2(e): folded into Q so softmax is exp2(st) with no per-elem mul.
#define QSCALE_LOG2E 0.18033688011112042f

// ---- helpers -------------------------------------------------------------

typedef __attribute__((address_space(3))) void as3_void;
typedef __attribute__((address_space(1))) void as1_void;

static __device__ __forceinline__ void async_load16(const void* g, void* l) {
  __builtin_amdgcn_global_load_lds((as1_void*)(uintptr_t)g, (as3_void*)(uintptr_t)l,
                                   16, 0, 0);
}

static __device__ __forceinline__ u16 f2bf(float f) {
  union { float f; unsigned int u; } v; v.f = f;
  unsigned int u = v.u;
  u += 0x7fffu + ((u >> 16) & 1u);   // RNE
  return (u16)(u >> 16);
}

static __device__ __forceinline__ u16x4 pack_bf4(float a, float b, float c, float d) {
#if __has_builtin(__builtin_amdgcn_cvt_pk_bf16_f32)
  union { u16x4 v4; bf16x2 v2[2]; } u;
  u.v2[0] = __builtin_amdgcn_cvt_pk_bf16_f32(a, b);
  u.v2[1] = __builtin_amdgcn_cvt_pk_bf16_f32(c, d);
  return u.v4;
#else
  u16x4 r; r[0] = f2bf(a); r[1] = f2bf(b); r[2] = f2bf(c); r[3] = f2bf(d);
  return r;
#endif
}

static __device__ __forceinline__ float fast_exp2(float x) {
#if __has_builtin(__builtin_amdgcn_exp2f)
  return __builtin_amdgcn_exp2f(x);
#else
  return exp2f(x);
#endif
}

// ---- fused: 4x weight transpose+convert (z=0..3) + x convert (z=4) -------

__global__ __launch_bounds__(256) void prep_kernel(
    const float* __restrict__ w0, const float* __restrict__ w1,
    const float* __restrict__ w2, const float* __restrict__ w3,
    u16* __restrict__ wout,
    const float* __restrict__ xin, u16* __restrict__ xout) {
  if (blockIdx.z == 4) {
    int blk = blockIdx.y * 16 + blockIdx.x;
    size_t base = (size_t)blk * 16384 + (size_t)threadIdx.x * 8;
#pragma unroll
    for (int r = 0; r < 8; r++) {
      size_t i = base + (size_t)r * 2048;
      float4 a = *(const float4*)(xin + i);
      float4 b = *(const float4*)(xin + i + 4);
      u16x8 o;
      o[0] = f2bf(a.x); o[1] = f2bf(a.y); o[2] = f2bf(a.z); o[3] = f2bf(a.w);
      o[4] = f2bf(b.x); o[5] = f2bf(b.y); o[6] = f2bf(b.z); o[7] = f2bf(b.w);
      *(u16x8*)(xout + i) = o;
    }
    return;
  }
  __shared__ u16 t[64][65];
  const float* in = (blockIdx.z == 0) ? w0 : (blockIdx.z == 1) ? w1
                    : (blockIdx.z == 2) ? w2 : w3;
  u16* oz = wout + (size_t)blockIdx.z * (1024 * 1024);
  const int tid = threadIdx.x;
  const int x = tid & 63, y0 = tid >> 6;
  const int bx = blockIdx.x * 64, by = blockIdx.y * 64;
#pragma unroll
  for (int p = 0; p < 16; p++) {
    int y = y0 + p * 4;
    t[y][x] = f2bf(in[(size_t)(by + y) * 1024 + bx + x]);
  }
  __syncthreads();
#pragma unroll
  for (int p = 0; p < 16; p++) {
    int r = y0 + p * 4;
    oz[(size_t)(bx + r) * 1024 + by + x] = t[x][r];
  }
}

// ---- QKV GEMM: C[4096][1024] = X @ Wz, Wz given transposed [N][K] --------
// 128x128 tile, BK=32, 4 waves, global_load_lds staging, XOR-swizzled octets.
// z==0 (Q): pre-scaled by QSCALE_LOG2E, row-major out.
// z==1 (K): row-major out.
// z==2 (V): written as V^T[bh][64][2048] via an LDS-transposed coalesced
//           epilogue (256B-contiguous segments).

__global__ __launch_bounds__(256, 3) void gemm_qkv_kernel(
    const u16* __restrict__ A, const u16* __restrict__ BT,
    u16* __restrict__ out, u16* __restrict__ outVT) {
  __shared__ u16 As[128 * 32];
  __shared__ u16 Bs[128 * 32];
  __shared__ u16 tb[64 * 136];       // V^T staging (z==2 epilogue only)
  const int tid = threadIdx.x;
  const int w = tid >> 6, lane = tid & 63;
  const int bm = blockIdx.y * 128, bn = blockIdx.x * 128;
  const int z = blockIdx.z;
  const int K = 1024, N = 1024;
  const u16* Bz = BT + (size_t)z * N * K;

  const int c0 = w * 2, c1 = c0 + 1;
  const int mA0 = c0 * 16 + (lane >> 2), mA1 = c1 * 16 + (lane >> 2);
  const int kg0 = (lane & 3) ^ ((mA0 >> 1) & 3);
  const int kg1 = (lane & 3) ^ ((mA1 >> 1) & 3);
  const u16* agp0 = A + (size_t)(bm + mA0) * K + kg0 * 8;
  const u16* agp1 = A + (size_t)(bm + mA1) * K + kg1 * 8;
  const u16* bgp0 = Bz + (size_t)(bn + mA0) * K + kg0 * 8;
  const u16* bgp1 = Bz + (size_t)(bn + mA1) * K + kg1 * 8;
  u16* ald0 = As + c0 * 512; u16* ald1 = As + c1 * 512;
  u16* bld0 = Bs + c0 * 512; u16* bld1 = Bs + c1 * 512;

  const int wm = (w >> 1) * 64, wn = (w & 1) * 64;
  floatx4 acc[4][4] = {};

  int a_off[4], b_off[4];
#pragma unroll
  for (int i = 0; i < 4; i++) {
    int m = wm + i * 16 + (lane & 15);
    a_off[i] = m * 32 + (((lane >> 4) ^ ((m >> 1) & 3)) * 8);
    int n = wn + i * 16 + (lane & 15);
    b_off[i] = n * 32 + (((lane >> 4) ^ ((n >> 1) & 3)) * 8);
  }

  for (int k0 = 0; k0 < K; k0 += 32) {
    __syncthreads();
    async_load16(agp0 + k0, ald0);
    async_load16(agp1 + k0, ald1);
    async_load16(bgp0 + k0, bld0);
    async_load16(bgp1 + k0, bld1);
    __syncthreads();
    bf16x8 af[4], bf[4];
#pragma unroll
    for (int i = 0; i < 4; i++) af[i] = *(const bf16x8*)(As + a_off[i]);
#pragma unroll
    for (int j = 0; j < 4; j++) bf[j] = *(const bf16x8*)(Bs + b_off[j]);
#pragma unroll
    for (int i = 0; i < 4; i++)
#pragma unroll
      for (int j = 0; j < 4; j++)
        acc[i][j] = MFMA16(af[i], bf[j], acc[i][j]);
  }

  // epilogue: C/D layout col=lane&15, row=(lane>>4)*4+reg  [m89]
  const int roff = (lane >> 4) * 4;
  const int coff = lane & 15;
  if (z == 2) {
    // V^T: two 64-col halves through padded LDS, then coalesced b128 stores
    const int b = bm >> 11, s0 = bm & 2047;
#pragma unroll
    for (int half = 0; half < 2; half++) {
      __syncthreads();
      if ((w & 1) == half) {
#pragma unroll
        for (int i = 0; i < 4; i++) {
          int s_local = wm + i * 16 + roff;
#pragma unroll
          for (int j = 0; j < 4; j++) {
            int c_local = j * 16 + coff;     // 0..63 within half
            u16x4 pk = pack_bf4(acc[i][j][0], acc[i][j][1],
                                acc[i][j][2], acc[i][j][3]);
            *(u16x4*)(tb + c_local * 136 + s_local) = pk;
          }
        }
      }
      __syncthreads();
      // store: 16 consecutive lanes cover one d-row's 128 s (256B contiguous)
#pragma unroll
      for (int p = 0; p < 4; p++) {
        int c_local = (tid >> 4) & 15;       // 0..15
        int row = p * 16 + c_local;          // 0..63
        int so = tid & 15;
        int cg = bn + half * 64 + row;
        int h = cg >> 6, d = cg & 63;
        u16x8 vv = *(const u16x8*)(tb + row * 136 + so * 8);
        *(u16x8*)(outVT + ((size_t)(b * 16 + h) * 64 + d) * 2048 + s0 + so * 8) = vv;
      }
    }
  } else {
    const float sc = (z == 0) ? QSCALE_LOG2E : 1.0f;
    u16* outz = out + (size_t)z * 4096 * 1024;
#pragma unroll
    for (int i = 0; i < 4; i++) {
      int r0 = bm + wm + i * 16 + roff;
#pragma unroll
      for (int j = 0; j < 4; j++) {
        int c = bn + wn + j * 16 + coff;
#pragma unroll
        for (int r = 0; r < 4; r++)
          outz[(size_t)(r0 + r) * N + c] = f2bf(acc[i][j][r] * sc);
      }
    }
  }
}

// ---- O GEMM: out[4096][1024] f32 = CTX @ Wo + bo -------------------------
// 128m x 64n tile, BK=32, 4 waves (2x2 of 64x32) -> 512 blocks = 2/CU.

__global__ __launch_bounds__(256, 2) void gemm_o_kernel(
    const u16* __restrict__ A, const u16* __restrict__ BT,
    const float* __restrict__ bias, float* __restrict__ out) {
  __shared__ u16 As[128 * 32];
  __shared__ u16 Bs[64 * 32];
  const int tid = threadIdx.x;
  const int w = tid >> 6, lane = tid & 63;
  const int bm = blockIdx.y * 128, bn = blockIdx.x * 64;
  const int K = 1024, N = 1024;

  const u16* gp[3]; u16* ld[3];
#pragma unroll
  for (int i = 0; i < 3; i++) {
    int c = w * 3 + i;
    if (c < 8) {
      int m = c * 16 + (lane >> 2);
      int kg = (lane & 3) ^ ((m >> 1) & 3);
      gp[i] = A + (size_t)(bm + m) * K + kg * 8;
      ld[i] = As + c * 512;
    } else {
      int cb = c - 8;
      int n = cb * 16 + (lane >> 2);
      int kg = (lane & 3) ^ ((n >> 1) & 3);
      gp[i] = BT + (size_t)(bn + n) * K + kg * 8;
      ld[i] = Bs + cb * 512;
    }
  }

  const int wm = (w >> 1) * 64, wn = (w & 1) * 32;
  floatx4 acc[4][2] = {};

  int a_off[4], b_off[2];
#pragma unroll
  for (int i = 0; i < 4; i++) {
    int m = wm + i * 16 + (lane & 15);
    a_off[i] = m * 32 + (((lane >> 4) ^ ((m >> 1) & 3)) * 8);
  }
#pragma unroll
  for (int j = 0; j < 2; j++) {
    int n = wn + j * 16 + (lane & 15);
    b_off[j] = n * 32 + (((lane >> 4) ^ ((n >> 1) & 3)) * 8);
  }

  for (int k0 = 0; k0 < K; k0 += 32) {
    __syncthreads();
    async_load16(gp[0] + k0, ld[0]);
    async_load16(gp[1] + k0, ld[1]);
    async_load16(gp[2] + k0, ld[2]);
    __syncthreads();
    bf16x8 af[4], bf[2];
#pragma unroll
    for (int i = 0; i < 4; i++) af[i] = *(const bf16x8*)(As + a_off[i]);
#pragma unroll
    for (int j = 0; j < 2; j++) bf[j] = *(const bf16x8*)(Bs + b_off[j]);
#pragma unroll
    for (int i = 0; i < 4; i++)
#pragma unroll
      for (int j = 0; j < 2; j++)
        acc[i][j] = MFMA16(af[i], bf[j], acc[i][j]);
  }

  const int roff = (lane >> 4) * 4;
  const int coff = lane & 15;
#pragma unroll
  for (int i = 0; i < 4; i++) {
    int r0 = bm + wm + i * 16 + roff;
#pragma unroll
    for (int j = 0; j < 2; j++) {
      int c = bn + wn + j * 16 + coff;
      float bv = bias[c];
#pragma unroll
      for (int r = 0; r < 4; r++)
        out[(size_t)(r0 + r) * N + c] = acc[i][j][r] + bv;
    }
  }
}

// ---- flash attention (no-max softmax, 512-thread blocks, s-split pairs) --
// Q (pre-scaled), K: [b*2048+s][1024] row-major bf16, head at col h*64.
// VT: [bh][64][2048] bf16.  ctx: [b][s][1024] bf16.
// Block = 8 waves over a 128q x 128s tile: wave (qq,sh) = q-quarter qq
// (32 rows in registers as B-operand) x s-half sh (64 cols).
// WHY 512 threads: the grid is 512 blocks (hard 2 blocks/CU cap).  Every
// R5-R10 variant ran 8 waves/CU = 2 waves/SIMD and was stall-bound with all
// pipes <40% (LDS traffic, conflicts, vmcnt drains each eliminated with no
// speedup).  8-wave blocks give 16 waves/CU = 4 waves/SIMD — doubling the
// latency hiding for MFMA/exp2/LDS dependency chains at unchanged grid.
// Per-wave work = R9's footprint (st[4][2], o[2][4], VGPR ~84).
// s-halves combine additively in the epilogue (no-max softmax => partial O
// and l just add) through the dead Ks/Vs space (exactly 2048 floatx4).
// Row-sum via MFMA vs all-ones.  XCD swizzle: bid&7 pins 4 heads' K/V into
// one XCD's L2 (FETCH 70 -> 12 MB measured).

__global__ __launch_bounds__(512, 4) void attn_kernel(
    const u16* __restrict__ Q, const u16* __restrict__ Kx,
    const u16* __restrict__ VT, u16* __restrict__ ctx) {
  // arena: Ks [128s][64d] | Vs [64d][128s] | Ps 8 x [32q][72]  = 68 KB
  __shared__ __align__(16) u16 lds[8192 + 8192 + 8 * 32 * 72];
  u16* Ks = lds;
  u16* Vs = lds + 8192;
  u16* Ps = lds + 16384;
  const int tid = threadIdx.x;
  const int w = tid >> 6, lane = tid & 63;
  const int qq = w >> 1, sh = w & 1;
  const int quad = lane >> 4;
  const int bid = blockIdx.x;
  const int bh = (bid >> 7) * 8 + (bid & 7);      // XCD-pinned head group
  const int q0 = ((bid >> 3) & 15) * 128;
  const int b = bh >> 4, h = bh & 15;
  const u16* Qh = Q + (size_t)b * 2048 * 1024 + h * 64;
  const u16* Kh = Kx + (size_t)b * 2048 * 1024 + h * 64;
  const u16* Vh = VT + (size_t)bh * 64 * 2048;

  // Q fragments: 32 q-rows/wave (B-operand: col=lane&15, k-octet=quad)
  const int qbase = q0 + qq * 32;
  bf16x8 qf[2][2];
#pragma unroll
  for (int qt = 0; qt < 2; qt++)
#pragma unroll
    for (int ks = 0; ks < 2; ks++)
      qf[qt][ks] = *(const bf16x8*)(Qh + (size_t)(qbase + qt * 16 + (lane & 15)) * 1024 +
                                    ks * 32 + quad * 8);

  bf16x8 onesf;
#pragma unroll
  for (int i = 0; i < 8; i++) onesf[i] = (__bf16)1.0f;
  const floatx4 zero4 = {};

  // staging: wave w owns Ks chunks {2w,2w+1} and Vs chunks {2w,2w+1}
  const u16* kgp[2]; const u16* vgp[2];
  u16* kld[2]; u16* vld[2];
#pragma unroll
  for (int i = 0; i < 2; i++) {
    int c = w * 2 + i;                 // 0..15
    int sl = c * 8 + (lane >> 3);
    int dg = (lane & 7) ^ (lane >> 3);
    kgp[i] = Kh + (size_t)sl * 1024 + dg * 8;
    kld[i] = Ks + c * 512;
    int dl = c * 4 + quad;
    int sg = (lane & 15) ^ (dl & 15);
    vgp[i] = Vh + (size_t)dl * 2048 + sg * 8;
    vld[i] = Vs + c * 512;
  }

  // K-fragment LDS bases for this wave's s-half (4 slabs of 16 s)
  const int slot_k0 = quad ^ (lane & 7);
  const int slot_k1 = (4 + quad) ^ (lane & 7);
  const u16* kf0_base = Ks + sh * 4096 + (lane & 15) * 64 + slot_k0 * 8;
  const u16* kf1_base = Ks + sh * 4096 + (lane & 15) * 64 + slot_k1 * 8;

  floatx4 o[2][4] = {};
  floatx4 lacc[2] = {};              // partial row sums (this s-half)
  u16* Pw = Ps + w * (32 * 72);
  const int qrow0 = (lane & 15) * 72;
  const int qrow1 = (16 + (lane & 15)) * 72;

  for (int t = 0; t < 16; t++) {
    const size_t k0 = (size_t)t * 128;
    __syncthreads();
#pragma unroll
    for (int i = 0; i < 2; i++) {
      async_load16(kgp[i] + k0 * 1024, kld[i]);
      async_load16(vgp[i] + k0, vld[i]);
    }
    __syncthreads();

    // QK for this wave's 4 slabs (batched: 16 MFMAs in flight)
    floatx4 st[4][2];
#pragma unroll
    for (int si = 0; si < 4; si++) {
      bf16x8 kf0 = *(const bf16x8*)(kf0_base + si * 1024);
      bf16x8 kf1 = *(const bf16x8*)(kf1_base + si * 1024);
#pragma unroll
      for (int qt = 0; qt < 2; qt++)
        st[si][qt] = MFMA16(kf1, qf[qt][1], MFMA16(kf0, qf[qt][0], zero4));
    }
    // p = exp2(st); pack + write P [q][s_local] (s_local = si*16 + quad*4)
#pragma unroll
    for (int si = 0; si < 4; si++) {
      u16x4 pk0 = pack_bf4(fast_exp2(st[si][0][0]), fast_exp2(st[si][0][1]),
                           fast_exp2(st[si][0][2]), fast_exp2(st[si][0][3]));
      u16x4 pk1 = pack_bf4(fast_exp2(st[si][1][0]), fast_exp2(st[si][1][1]),
                           fast_exp2(st[si][1][2]), fast_exp2(st[si][1][3]));
      *(u16x4*)(Pw + qrow0 + si * 16 + quad * 4) = pk0;
      *(u16x4*)(Pw + qrow1 + si * 16 + quad * 4) = pk1;
    }

    // O += P . V over this s-half's two 32-s blocks
#pragma unroll
    for (int ksl = 0; ksl < 2; ksl++) {
      int kb = sh * 2 + ksl;
      bf16x8 vf[4];
#pragma unroll
      for (int jt = 0; jt < 4; jt++) {
        int d = jt * 16 + (lane & 15);
        int slot = (kb * 4 + quad) ^ (d & 15);
        vf[jt] = *(const bf16x8*)(Vs + d * 128 + slot * 8);
      }
#pragma unroll
      for (int qt = 0; qt < 2; qt++) {
        bf16x8 pf = *(const bf16x8*)(Pw + (qt * 16 + (lane & 15)) * 72 +
                                     ksl * 32 + quad * 8);
#pragma unroll
        for (int jt = 0; jt < 4; jt++)
          o[qt][jt] = MFMA16(pf, vf[jt], o[qt][jt]);
        lacc[qt] = MFMA16(pf, onesf, lacc[qt]);
      }
    }
  }

  // combine s-halves: sh==1 dumps O,l; sh==0 adds + stores.
  // dump region = Ks+Vs (32768 B = 2048 floatx4, exactly 4qq*2qt*4jt*64).
  __syncthreads();
  floatx4* dump  = (floatx4*)lds;
  floatx4* ldump = (floatx4*)(lds + 16384);  // Ps region (512 floatx4 used)
  if (sh == 1) {
    int base = qq * 512;
#pragma unroll
    for (int qt = 0; qt < 2; qt++)
#pragma unroll
      for (int jt = 0; jt < 4; jt++)
        dump[base + (qt * 4 + jt) * 64 + lane] = o[qt][jt];
#pragma unroll
    for (int qt = 0; qt < 2; qt++)
      ldump[qq * 128 + qt * 64 + lane] = lacc[qt];
  }
  __syncthreads();
  if (sh == 0) {
    int base = qq * 512;
#pragma unroll
    for (int qt = 0; qt < 2; qt++)
#pragma unroll
      for (int jt = 0; jt < 4; jt++)
        o[qt][jt] += dump[base + (qt * 4 + jt) * 64 + lane];
#pragma unroll
    for (int qt = 0; qt < 2; qt++)
      lacc[qt] += ldump[qq * 128 + qt * 64 + lane];
    // epilogue: ctx[b][s][h*64+d] bf16; lacc rows coincide with o rows
#pragma unroll
    for (int qt = 0; qt < 2; qt++)
#pragma unroll
      for (int r = 0; r < 4; r++) {
        float inv = 1.0f / lacc[qt][r];
        int s = qbase + qt * 16 + quad * 4 + r;
#pragma unroll
        for (int j = 0; j < 4; j++) {
          int c = h * 64 + j * 16 + (lane & 15);
          ctx[(size_t)(b * 2048 + s) * 1024 + c] = f2bf(o[qt][j][r] * inv);
        }
      }
  }
}

// ---- launch --------------------------------------------------------------
// ws layout (u16 elements, MM = 1024*1024):
//   [0,3MM)    WqT,WkT,WvT bf16        [3MM,4MM)  WoT bf16
//   [4MM,8MM)  x converted to bf16     [8MM,20MM) Q,K row-major (V slot unused)
//   [20MM,24MM) V^T bf16               [24MM,28MM) ctx bf16

extern "C" void kernel_launch(void* const* d_in, const int* in_sizes, int n_in,
                              void* d_out, int out_size, void* d_ws, size_t ws_size,
                              hipStream_t stream) {
  (void)in_sizes; (void)n_in; (void)out_size; (void)ws_size;
  const float* x  = (const float*)d_in[0];
  const float* Wq = (const float*)d_in[1];
  const float* Wk = (const float*)d_in[2];
  const float* Wv = (const float*)d_in[3];
  const float* Wo = (const float*)d_in[4];
  const float* bo = (const float*)d_in[5];
  u16* ws = (u16*)d_ws;
  const size_t MM = 1024 * 1024;
  u16* WT  = ws;             // 3 x [1024][1024] (Wq,Wk,Wv transposed)
  u16* WoT = ws + 3 * MM;    // [1024][1024]
  u16* Xb  = ws + 4 * MM;    // [4096][1024]
  u16* QKV = ws + 8 * MM;    // Q,K row-major [4096][1024] each
  u16* VTp = ws + 20 * MM;   // [32][64][2048]
  u16* CTX = ws + 24 * MM;   // [4096][1024]

  dim3 blk(256);
  prep_kernel<<<dim3(16, 16, 5), blk, 0, stream>>>(Wq, Wk, Wv, Wo, WT, x, Xb);
  gemm_qkv_kernel<<<dim3(8, 32, 3), blk, 0, stream>>>(Xb, WT, QKV, VTp);
  attn_kernel<<<dim3(512, 1, 1), dim3(512), 0, stream>>>(QKV, QKV + 4 * MM, VTp, CTX);
  gemm_o_kernel<<<dim3(16, 32, 1), blk, 0, stream>>>(CTX, WoT, bo, (float*)d_out);
}